// Round 4
// baseline (2175.220 us; speedup 1.0000x reference)
//
#include <hip/hip_runtime.h>
#include <stdint.h>

// Problem constants
#define NBATCH 16
#define NNODE  20
#define TSTEPS 63      // T-1
#define NEDGE  380
#define HID    256
#define RS     280     // hst row stride in shorts (16B-aligned rows, phase-clean b128)

typedef __bf16 bf16x8 __attribute__((ext_vector_type(8)));
typedef float  f32x4  __attribute__((ext_vector_type(4)));

__device__ __forceinline__ float bf2f(unsigned short u){
  union { unsigned int i; float f; } v; v.i = ((unsigned int)u) << 16; return v.f;
}
__device__ __forceinline__ unsigned short f2bf(float f){
  union { float f; unsigned int i; } v; v.f = f;
  return (unsigned short)((v.i + 0x7FFFu + ((v.i >> 16) & 1u)) >> 16);
}
__device__ __forceinline__ bf16x8 as_frag(uint4 v){
  union { uint4 u; bf16x8 b; } c; c.u = v; return c.b;
}
__device__ __forceinline__ float sigmf(float x){ return 1.0f/(1.0f+__expf(-x)); }
__device__ __forceinline__ float tanh_f(float x){ float e=__expf(2.0f*x); return (e-1.0f)/(e+1.0f); }

// Relaxed agent-scope ops: per-access sc1 (LLC = coherence point), no cache-wide inv/wb.
__device__ __forceinline__ unsigned long long load_ax(const unsigned long long* p){
  return __hip_atomic_load(p, __ATOMIC_RELAXED, __HIP_MEMORY_SCOPE_AGENT);
}
__device__ __forceinline__ void store_ax(unsigned long long* p, unsigned long long v){
  __hip_atomic_store(p, v, __ATOMIC_RELAXED, __HIP_MEMORY_SCOPE_AGENT);
}
__device__ __forceinline__ unsigned int load_ax32(const unsigned int* p){
  return __hip_atomic_load(p, __ATOMIC_RELAXED, __HIP_MEMORY_SCOPE_AGENT);
}
__device__ __forceinline__ void wait_vm0(){ asm volatile("s_waitcnt vmcnt(0)" ::: "memory"); }

// In-register 4x4 gate transpose among lanes cl, cl^1, cl^2, cl^3 (gate-interleaved cols).
// in: v[r] = preact(row quad*4+r) for (gate=cl&3, hsub=cl>>2)
// out: v[g] = preact gate g for (row quad*4+(cl&3), hsub=cl>>2)
__device__ __forceinline__ void xpose4(f32x4& v, int cl){
  float s0 = __shfl_xor((float)v[1], 1), s1 = __shfl_xor((float)v[0], 1);
  float s2 = __shfl_xor((float)v[3], 1), s3 = __shfl_xor((float)v[2], 1);
  bool b0 = (cl & 1);
  float a0 = b0 ? s0 : v[0], a1 = b0 ? v[1] : s1;
  float a2 = b0 ? s2 : v[2], a3 = b0 ? v[3] : s3;
  float t0 = __shfl_xor(a2, 2), t1 = __shfl_xor(a3, 2);
  float t2 = __shfl_xor(a0, 2), t3 = __shfl_xor(a1, 2);
  bool b1 = (cl & 2);
  v[0] = b1 ? t0 : a0; v[1] = b1 ? t1 : a1;
  v[2] = b1 ? a2 : t2; v[3] = b1 ? a3 : t3;
}

// ---------------------------------------------------------------------------
// prep_a: combined weights (fp32) + interleaved biases + zero counters/Afin.
__global__ __launch_bounds__(256) void prep_a(
    const float* __restrict__ We, const float* __restrict__ Wei,
    const float* __restrict__ Wm, const float* __restrict__ Wmi,
    const float* __restrict__ bm, const float* __restrict__ bmi, const float* __restrict__ bmh,
    const float* __restrict__ be, const float* __restrict__ bei, const float* __restrict__ beh,
    float* __restrict__ Wse, float* __restrict__ Wre, float* __restrict__ WcmGI,
    float* __restrict__ bcmGI, float* __restrict__ bceGI,
    float* __restrict__ Afin, unsigned int* __restrict__ ectr, unsigned int* __restrict__ mctr){
  int bid = blockIdx.x, tid = threadIdx.x;
  if (bid < 2048){
    int idx = bid*256 + tid;
    int half = idx >> 18;
    int j = idx & 262143;
    int k = j >> 10, nn = j & 1023;
    const float* Wrow = We + (half*256 + k)*128;
    float s = 0.f;
    for (int d = 0; d < 128; ++d) s += Wrow[d] * Wei[d*1024 + nn];
    (half ? Wre : Wse)[k*1024 + nn] = s;
  } else if (bid < 2064){
    int idx = (bid-2048)*256 + tid;
    int d = idx >> 10, ci = idx & 1023;
    int col = (ci & 3)*256 + (ci >> 2);
    float s = 0.f;
    for (int j = 0; j < 128; ++j) s += Wm[d*128 + j] * Wmi[j*1024 + col];
    WcmGI[idx] = s;
  } else if (bid < 2068){
    int ci = (bid-2064)*256 + tid;
    int col = (ci & 3)*256 + (ci >> 2);
    float s = bmi[col] + bmh[col];
    for (int j = 0; j < 128; ++j) s += bm[j] * Wmi[j*1024 + col];
    bcmGI[ci] = s;
  } else if (bid < 2072){
    int ci = (bid-2068)*256 + tid;
    int col = (ci & 3)*256 + (ci >> 2);
    float s = bei[col] + beh[col];
    for (int j = 0; j < 128; ++j) s += be[j] * Wei[j*1024 + col];
    bceGI[ci] = s;
  } else if (bid == 2072){
    ectr[tid] = 0u;
    if (tid < 128) mctr[tid] = 0u;
  } else {
    int idx = (bid-2073)*256 + tid;
    if (idx < NBATCH*NEDGE) Afin[idx] = 0.f;
  }
}

// ---------------------------------------------------------------------------
// prep_b packing (verified R2/R3).
__device__ __forceinline__ void pack_gi(const float* __restrict__ W,
                                        unsigned short* __restrict__ dst, int id){
  int lane = id & 63, kt = (id >> 6) & 7, tt = (id >> 9) & 1, w = (id >> 10) & 7, nb = id >> 13;
  int cl = lane & 15, q = lane >> 4;
  int gcol = (cl & 3)*256 + nb*64 + (w*2 + tt)*4 + (cl >> 2);
  int k0 = kt*32 + q*8;
  unsigned int wb[4];
  #pragma unroll
  for (int p = 0; p < 4; ++p){
    unsigned short a = f2bf(W[(k0+2*p  )*1024 + gcol]);
    unsigned short b = f2bf(W[(k0+2*p+1)*1024 + gcol]);
    wb[p] = (unsigned int)a | ((unsigned int)b << 16);
  }
  ((uint4*)dst)[id] = make_uint4(wb[0], wb[1], wb[2], wb[3]);
}

__device__ __forceinline__ void pack_one(const float* __restrict__ S,
                                         unsigned short* __restrict__ dst, int id, int n){
  int lane = id & 63, kt = (id >> 6) & 7;
  int k0 = kt*32 + ((lane >> 4) << 3);
  unsigned int wb[4];
  #pragma unroll
  for (int p = 0; p < 4; ++p){
    unsigned short a = f2bf(S[(k0+2*p  )*1024 + n]);
    unsigned short b = f2bf(S[(k0+2*p+1)*1024 + n]);
    wb[p] = (unsigned int)a | ((unsigned int)b << 16);
  }
  ((uint4*)dst)[id] = make_uint4(wb[0], wb[1], wb[2], wb[3]);
}

__global__ __launch_bounds__(256) void prep_b(
    const float* __restrict__ Wmh, const float* __restrict__ Weh,
    const float* __restrict__ Wse, const float* __restrict__ Wre,
    unsigned short* __restrict__ pWmh, unsigned short* __restrict__ pWeh,
    unsigned short* __restrict__ pWsr){
  int gid = blockIdx.x*256 + threadIdx.x;
  if (gid < 32768){
    pack_gi(Wmh, pWmh, gid);
  } else if (gid < 65536){
    pack_gi(Weh, pWeh, gid - 32768);
  } else {
    int id = gid - 65536;
    int ng = (id >> 9)*16 + (id & 15);
    const float* S = (ng < 1024) ? Wse : Wre;
    pack_one(S, pWsr, id, ng & 1023);
  }
}

// ---------------------------------------------------------------------------
// motion_lstm: grid 128 = 32 m (10 seqs) x 4 n. 512 thr = 8 waves.
// dbuf hst, 1 barrier/step, wave-autonomous publish, per-block counters.
__global__ __launch_bounds__(512, 2) void motion_lstm(
    const float* __restrict__ X, const float* __restrict__ WcmGI,
    const float* __restrict__ bcmGI, const unsigned short* __restrict__ pWmh,
    unsigned short* __restrict__ hm, unsigned short* __restrict__ mb,
    unsigned int* __restrict__ mctr){
  __shared__ __align__(16) unsigned short hst[2][16*RS];   // 17920 B
  __shared__ float dxs[10*252];
  __shared__ __align__(16) float sWc[4*256];
  __shared__ __align__(16) float sbc[256];
  int tid = threadIdx.x, lane = tid & 63, w = tid >> 6;
  int l15 = lane & 15, quad = lane >> 4;
  int m = blockIdx.x & 31, n = blockIdx.x >> 5;
  int s0 = m*10;
  unsigned int* ctrs = mctr + m*4;

  uint4 wreg[2][8];
  #pragma unroll
  for (int tt = 0; tt < 2; ++tt)
    #pragma unroll
    for (int kt = 0; kt < 8; ++kt)
      wreg[tt][kt] = ((const uint4*)pWmh)[(((n*8 + w)*2 + tt)*8 + kt)*64 + lane];

  uint4 z4 = make_uint4(0,0,0,0);
  for (int i = tid; i < 1120; i += 512) ((uint4*)hst)[i] = z4;
  for (int i = tid; i < 1024; i += 512) sWc[i] = WcmGI[(i >> 8)*1024 + n*256 + (i & 255)];
  if (tid < 256) sbc[tid] = bcmGI[n*256 + tid];
  for (int i = tid; i < 2520; i += 512){
    int sl = i / 252; int r = i % 252; int t = r >> 2; int d = r & 3;
    const float* Xp = X + (((size_t)(s0 + sl)*64 + t)*4 + d);
    dxs[i] = Xp[4] - Xp[0];
  }
  __syncthreads();

  float bb[2] = { sbc[(w*2+0)*16 + l15], sbc[(w*2+1)*16 + l15] };
  int row = quad*4 + (l15 & 3);
  int hsub = l15 >> 2;
  int slr = row < 10 ? row : 9;
  float ce[2] = {0.f, 0.f};

  for (int t = 0; t < TSTEPS; ++t){
    int par = t & 1, nxt = par ^ 1;
    if (t > 0){
      unsigned int tgt = 8u*(unsigned)t;
      while (1){
        unsigned int c0 = load_ax32(ctrs+0), c1 = load_ax32(ctrs+1);
        unsigned int c2 = load_ax32(ctrs+2), c3 = load_ax32(ctrs+3);
        if (c0 >= tgt && c1 >= tgt && c2 >= tgt && c3 >= tgt) break;
        __builtin_amdgcn_s_sleep(1);
      }
      const unsigned long long* mbp = (const unsigned long long*)mb
          + ((size_t)((t-1)&1)*32 + m)*16*64;
      unsigned long long pv[2]; int po[2] = {-1,-1};
      #pragma unroll
      for (int j = 0; j < 2; ++j){
        int i = tid + j*512;                   // 0..767: 3 slices x 256 ull
        if (i < 768){
          int which = i >> 8, jj = i & 255;
          int r = jj >> 4, c = jj & 15;
          int np = which + (which >= n ? 1 : 0);
          pv[j] = load_ax(&mbp[(size_t)r*64 + np*16 + c]);
          po[j] = r*RS + np*64 + c*4;
        }
      }
      #pragma unroll
      for (int j = 0; j < 2; ++j)
        if (po[j] >= 0) *(unsigned long long*)&hst[par][po[j]] = pv[j];
    }
    __syncthreads();                           // the ONE barrier per step

    f32x4 acc[2];
    acc[0] = (f32x4){bb[0],bb[0],bb[0],bb[0]};
    acc[1] = (f32x4){bb[1],bb[1],bb[1],bb[1]};
    #pragma unroll
    for (int kt = 0; kt < 8; ++kt){
      bf16x8 a = as_frag(*(const uint4*)&hst[par][l15*RS + kt*32 + quad*8]);
      acc[0] = __builtin_amdgcn_mfma_f32_16x16x32_bf16(a, as_frag(wreg[0][kt]), acc[0], 0, 0, 0);
      acc[1] = __builtin_amdgcn_mfma_f32_16x16x32_bf16(a, as_frag(wreg[1][kt]), acc[1], 0, 0, 0);
    }

    f32x4 dxv = *(const f32x4*)&dxs[slr*252 + t*4];
    #pragma unroll
    for (int tt = 0; tt < 2; ++tt){
      int tl = w*2 + tt;
      f32x4 v = acc[tt];
      xpose4(v, l15);
      #pragma unroll
      for (int d = 0; d < 4; ++d){
        f32x4 wv = *(const f32x4*)&sWc[d*256 + tl*16 + hsub*4];
        v[0] += dxv[d]*wv[0]; v[1] += dxv[d]*wv[1];
        v[2] += dxv[d]*wv[2]; v[3] += dxv[d]*wv[3];
      }
      float iv = sigmf(v[0]), fv = sigmf(v[1]), gg = tanh_f(v[2]), ov = sigmf(v[3]);
      float cc = fv*ce[tt] + iv*gg; ce[tt] = cc;
      unsigned short hb16 = f2bf(ov*tanh_f(cc));
      if (t < 62) hst[nxt][row*RS + n*64 + tl*4 + hsub] = hb16;
      if (row < 10)
        hm[(((size_t)(s0 + row)*63) + t)*256 + n*64 + tl*4 + hsub] = hb16;
    }
    if (t < 62){
      unsigned long long* mbc = (unsigned long long*)mb
          + ((size_t)(t&1)*32 + m)*16*64;
      if (lane < 32){
        int tlg = lane >> 4, r = lane & 15;
        unsigned long long v = *(const unsigned long long*)&hst[nxt][r*RS + n*64 + (w*2+tlg)*4];
        store_ax(&mbc[(size_t)r*64 + n*16 + w*2 + tlg], v);
      }
      wait_vm0();
      if ((tid & 63) == 0)
        __hip_atomic_fetch_add(&ctrs[n], 1u, __ATOMIC_RELAXED, __HIP_MEMORY_SCOPE_AGENT);
    }
  }
}

// ---------------------------------------------------------------------------
// gsr_gemm: gsr = hm @ [Wse|Wre] (M=20160,N=2048,K=256), bf16 out,
// gate-interleaved per half: col' = half*1024 + hcol*4 + gate. (verified)
__global__ __launch_bounds__(256) void gsr_gemm(
    const unsigned short* __restrict__ hm, const unsigned short* __restrict__ pWsr,
    unsigned short* __restrict__ gsr){
  int tid = threadIdx.x, lane = tid & 63, wid = tid >> 6;
  int l15 = lane & 15, quad = lane >> 4;
  int bm = blockIdx.x % 315, bn = blockIdx.x / 315;
  int rowbase = bm*64 + (wid >> 1)*32;
  int ntbase  = bn*8  + (wid & 1)*4;
  f32x4 acc[2][4] = {};
  #pragma unroll
  for (int kt = 0; kt < 8; ++kt){
    bf16x8 af[2];
    #pragma unroll
    for (int mt = 0; mt < 2; ++mt){
      int r = rowbase + mt*16 + l15;
      af[mt] = as_frag(*(const uint4*)&hm[(size_t)r*256 + kt*32 + quad*8]);
    }
    #pragma unroll
    for (int nt = 0; nt < 4; ++nt){
      bf16x8 bfr = as_frag(*(const uint4*)&pWsr[(((size_t)(ntbase+nt)*8 + kt)*64 + lane)*8]);
      #pragma unroll
      for (int mt = 0; mt < 2; ++mt)
        acc[mt][nt] = __builtin_amdgcn_mfma_f32_16x16x32_bf16(af[mt], bfr, acc[mt][nt], 0, 0, 0);
    }
  }
  #pragma unroll
  for (int mt = 0; mt < 2; ++mt)
    #pragma unroll
    for (int nt = 0; nt < 4; ++nt){
      int col = (ntbase+nt)*16 + l15;
      int half = col >> 10, ch = col & 1023;
      int colp = (half << 10) | ((ch & 255)*4 + (ch >> 8));
      #pragma unroll
      for (int r = 0; r < 4; ++r){
        int row = rowbase + mt*16 + quad*4 + r;
        gsr[(size_t)row*2048 + colp] = f2bf(acc[mt][nt][r]);
      }
    }
}

// ---------------------------------------------------------------------------
// edge_lstm: grid 256 = 16 b x 4 m (95 edges) x 4 n. 512 thr = 8 waves.
// xg via extra MFMA K-tile (one-hot A, gsr staged in B-frag layout), dbuf hst,
// 1 barrier/step, wave-autonomous publish.
__device__ __forceinline__ void stage_gxb(const unsigned short* __restrict__ gsr,
                                          unsigned short* __restrict__ gxbuf,
                                          int tid, int b, int m, int n, int tq){
  for (int i = tid; i < 400; i += 512){
    int kk = i >> 4, c8 = i & 15;
    int node = kk < 5 ? m*5 + kk : kk - 5;
    int off  = kk < 5 ? 0 : 1024;
    uint4 v = *(const uint4*)&gsr[((size_t)(b*20 + node)*63 + tq)*2048 + off + n*256 + c8*8];
    unsigned short* bp = &gxbuf[(c8>>1)*512 + (c8&1)*256 + kk];
    bp[0]   = (unsigned short)(v.x);
    bp[32]  = (unsigned short)(v.x >> 16);
    bp[64]  = (unsigned short)(v.y);
    bp[96]  = (unsigned short)(v.y >> 16);
    bp[128] = (unsigned short)(v.z);
    bp[160] = (unsigned short)(v.z >> 16);
    bp[192] = (unsigned short)(v.w);
    bp[224] = (unsigned short)(v.w >> 16);
  }
}

__global__ __launch_bounds__(512, 2) void edge_lstm(
    const unsigned short* __restrict__ gsr, const float* __restrict__ bceGI,
    const unsigned short* __restrict__ pWeh, const float* __restrict__ Wf,
    unsigned short* __restrict__ hb, float* __restrict__ Afin,
    unsigned int* __restrict__ ectr){
  __shared__ __align__(16) unsigned short hst[2][96*RS];   // 107520 B
  __shared__ __align__(16) unsigned short gxb[2][8192];    // 32768 B
  __shared__ __align__(16) float sbce[256];
  __shared__ __align__(16) float sWf[64];
  int tid = threadIdx.x, lane = tid & 63, w = tid >> 6;
  int l15 = lane & 15, quad = lane >> 4;
  int bid = blockIdx.x;
  int n = bid >> 6, G = bid & 63, b = G >> 2, m = G & 3;
  int e0 = m*95;
  unsigned int* ctrs = ectr + G*4;

  uint4 wreg[2][8];
  #pragma unroll
  for (int tt = 0; tt < 2; ++tt)
    #pragma unroll
    for (int kt = 0; kt < 8; ++kt)
      wreg[tt][kt] = ((const uint4*)pWeh)[(((n*8 + w)*2 + tt)*8 + kt)*64 + lane];

  // one-hot A fragments for the xg K-tile (k<5 sender, 5<=k<25 receiver)
  uint4 aoh[6];
  #pragma unroll
  for (int mt = 0; mt < 6; ++mt){
    int row = mt*16 + l15;
    int e = e0 + (row < 95 ? row : 94);
    int s = e / 19; int rr = e - s*19;
    int sr = s - m*5;
    int rc = rr + (rr >= s ? 1 : 0);
    unsigned int wd[4];
    #pragma unroll
    for (int p = 0; p < 4; ++p){
      int k0 = quad*8 + 2*p, k1 = k0 + 1;
      unsigned short a0 = ((k0 < 5) ? (sr == k0) : (k0 < 25 && rc == k0-5)) ? 0x3F80 : 0;
      unsigned short a1 = ((k1 < 5) ? (sr == k1) : (k1 < 25 && rc == k1-5)) ? 0x3F80 : 0;
      wd[p] = (unsigned int)a0 | ((unsigned int)a1 << 16);
    }
    aoh[mt] = make_uint4(wd[0], wd[1], wd[2], wd[3]);
  }

  if (tid < 256) sbce[tid] = bceGI[n*256 + tid];
  if (tid < 64)  sWf[tid]  = Wf[n*64 + tid];
  uint4 z4 = make_uint4(0,0,0,0);
  for (int i = tid; i < 13440; i += 512) ((uint4*)hst)[i] = z4;
  for (int i = tid; i < 2048; i += 512) ((uint4*)gxb)[i] = z4;
  __syncthreads();

  float bb[2]  = { sbce[(w*2+0)*16 + l15], sbce[(w*2+1)*16 + l15] };
  float wfr[2] = { sWf[(w*2+0)*4 + (l15>>2)], sWf[(w*2+1)*4 + (l15>>2)] };

  stage_gxb(gsr, &gxb[0][0], tid, b, m, n, 0);

  float ce[2][6]; float epi[6];
  #pragma unroll
  for (int mt = 0; mt < 6; ++mt){ ce[0][mt] = 0.f; ce[1][mt] = 0.f; epi[mt] = 0.f; }

  for (int t = 0; t < TSTEPS; ++t){
    int par = t & 1, nxt = par ^ 1;
    if (t > 0){
      unsigned int tgt = 8u*(unsigned)t;
      while (1){
        unsigned int c0 = load_ax32(ctrs+0), c1 = load_ax32(ctrs+1);
        unsigned int c2 = load_ax32(ctrs+2), c3 = load_ax32(ctrs+3);
        if (c0 >= tgt && c1 >= tgt && c2 >= tgt && c3 >= tgt) break;
        __builtin_amdgcn_s_sleep(1);
      }
      const unsigned long long* hbp = (const unsigned long long*)hb
          + (((size_t)((t-1)&1)*16 + b)*4 + m)*96*64;
      unsigned long long pv[9]; int po[9];
      #pragma unroll
      for (int j = 0; j < 9; ++j){
        int i = tid + j*512;                   // 0..4607: 3 slices x 1536 ull
        int which = i / 1536, jj = i - which*1536;
        int r = jj >> 4, c = jj & 15;
        int np = which + (which >= n ? 1 : 0);
        pv[j] = load_ax(&hbp[(size_t)r*64 + np*16 + c]);
        po[j] = r*RS + np*64 + c*4;
      }
      #pragma unroll
      for (int j = 0; j < 9; ++j)
        *(unsigned long long*)&hst[par][po[j]] = pv[j];
    }
    if (t + 1 < TSTEPS)
      stage_gxb(gsr, &gxb[nxt][0], tid, b, m, n, t+1);
    __syncthreads();                           // the ONE barrier per step

    f32x4 acc[2][6];
    #pragma unroll
    for (int mt = 0; mt < 6; ++mt){
      acc[0][mt] = (f32x4){bb[0],bb[0],bb[0],bb[0]};
      acc[1][mt] = (f32x4){bb[1],bb[1],bb[1],bb[1]};
    }
    #pragma unroll
    for (int kt = 0; kt < 8; ++kt){
      bf16x8 a[6];
      #pragma unroll
      for (int mt = 0; mt < 6; ++mt)
        a[mt] = as_frag(*(const uint4*)&hst[par][(mt*16 + l15)*RS + kt*32 + quad*8]);
      #pragma unroll
      for (int mt = 0; mt < 6; ++mt){
        acc[0][mt] = __builtin_amdgcn_mfma_f32_16x16x32_bf16(a[mt], as_frag(wreg[0][kt]), acc[0][mt], 0, 0, 0);
        acc[1][mt] = __builtin_amdgcn_mfma_f32_16x16x32_bf16(a[mt], as_frag(wreg[1][kt]), acc[1][mt], 0, 0, 0);
      }
    }
    {
      bf16x8 bx0 = as_frag(*(const uint4*)&gxb[par][(w*2+0)*512 + l15*32 + quad*8]);
      bf16x8 bx1 = as_frag(*(const uint4*)&gxb[par][(w*2+1)*512 + l15*32 + quad*8]);
      #pragma unroll
      for (int mt = 0; mt < 6; ++mt){
        acc[0][mt] = __builtin_amdgcn_mfma_f32_16x16x32_bf16(as_frag(aoh[mt]), bx0, acc[0][mt], 0, 0, 0);
        acc[1][mt] = __builtin_amdgcn_mfma_f32_16x16x32_bf16(as_frag(aoh[mt]), bx1, acc[1][mt], 0, 0, 0);
      }
    }

    #pragma unroll
    for (int tt = 0; tt < 2; ++tt){
      int tl = w*2 + tt;
      #pragma unroll
      for (int mt = 0; mt < 6; ++mt){
        f32x4 v = acc[tt][mt];
        xpose4(v, l15);
        float iv = sigmf(v[0]), fv = sigmf(v[1]), gg = tanh_f(v[2]), ov = sigmf(v[3]);
        float cc = fv*ce[tt][mt] + iv*gg; ce[tt][mt] = cc;
        float h = ov*tanh_f(cc);
        if (t < 62){
          int row = mt*16 + quad*4 + (l15 & 3);
          hst[nxt][row*RS + n*64 + tl*4 + (l15>>2)] = f2bf(h);
        } else {
          epi[mt] += h * wfr[tt];
        }
      }
    }
    if (t < 62){
      unsigned long long* hbc = (unsigned long long*)hb
          + (((size_t)(t&1)*16 + b)*4 + m)*96*64;
      #pragma unroll
      for (int k = 0; k < 3; ++k){
        int idx = lane + k*64;                 // 0..191: 2 tiles x 96 rows
        int tlg = idx / 96, r = idx - tlg*96;
        unsigned long long v = *(const unsigned long long*)&hst[nxt][r*RS + n*64 + (w*2+tlg)*4];
        store_ax(&hbc[(size_t)r*64 + n*16 + w*2 + tlg], v);
      }
      wait_vm0();
      if ((tid & 63) == 0)
        __hip_atomic_fetch_add(&ctrs[n], 1u, __ATOMIC_RELAXED, __HIP_MEMORY_SCOPE_AGENT);
    }
  }
  // epilogue: reduce over hsub lanes (xor 4, 8), one atomic per (row, wave)
  #pragma unroll
  for (int mt = 0; mt < 6; ++mt){
    float v = epi[mt];
    v += __shfl_xor(v, 4);
    v += __shfl_xor(v, 8);
    if (l15 < 4){
      int row = mt*16 + quad*4 + l15;
      if (row < 95)
        atomicAdd(&Afin[b*380 + e0 + row], v);
    }
  }
}

// ---------------------------------------------------------------------------
// finalize
__global__ __launch_bounds__(256) void finalize(const float* __restrict__ Afin,
                                                const float* __restrict__ bfp,
                                                float* __restrict__ out){
  int idx = blockIdx.x*256 + threadIdx.x;
  if (idx >= 16*400) return;
  int b = idx / 400; int ij = idx % 400; int i = ij / 20; int j = ij % 20;
  float v = 0.f;
  if (i != j){
    int e1 = i*19 + j - (j > i ? 1 : 0);
    int e2 = j*19 + i - (i > j ? 1 : 0);
    float bf = bfp[0];
    v = 0.5f*(sigmf(Afin[b*380 + e1] + bf) + sigmf(Afin[b*380 + e2] + bf));
  }
  out[idx] = v;
}

// ---------------------------------------------------------------------------
extern "C" void kernel_launch(void* const* d_in, const int* in_sizes, int n_in,
                              void* d_out, int out_size, void* d_ws, size_t ws_size,
                              hipStream_t stream){
  (void)in_sizes; (void)n_in; (void)out_size; (void)ws_size;
  const float* X   = (const float*)d_in[0];
  const float* Wm  = (const float*)d_in[3];
  const float* bm  = (const float*)d_in[4];
  const float* Wmi = (const float*)d_in[5];
  const float* bmi = (const float*)d_in[6];
  const float* Wmh = (const float*)d_in[7];
  const float* bmh = (const float*)d_in[8];
  const float* We  = (const float*)d_in[9];
  const float* be  = (const float*)d_in[10];
  const float* Wei = (const float*)d_in[11];
  const float* bei = (const float*)d_in[12];
  const float* Weh = (const float*)d_in[13];
  const float* beh = (const float*)d_in[14];
  const float* Wf  = (const float*)d_in[15];
  const float* bfp = (const float*)d_in[16];

  char* ws = (char*)d_ws;
  float* Wse   = (float*)(ws + 0);                          // 1 MB
  float* Wre   = (float*)(ws + 1048576);                    // 1 MB
  float* WcmGI = (float*)(ws + 2097152);                    // 16 KB
  float* bcmGI = (float*)(ws + 2113536);                    // 4 KB
  float* bceGI = (float*)(ws + 2117632);                    // 4 KB
  unsigned short* pWmh = (unsigned short*)(ws + 2121728);   // 512 KB
  unsigned short* pWeh = (unsigned short*)(ws + 2646016);   // 512 KB
  unsigned short* pWsr = (unsigned short*)(ws + 3170304);   // 1 MB
  unsigned short* hm   = (unsigned short*)(ws + 4218880);   // 10.3 MB
  unsigned short* gsr  = (unsigned short*)(ws + 14540800);  // 82.6 MB
  unsigned short* hb   = (unsigned short*)(ws + 97116160);  // 6.3 MB (edge exchange)
  unsigned short* mb   = hb;                                // aliased: disjoint lifetime
  float* Afin          = (float*)(ws + 103407616);          // 24 KB
  unsigned int* ectr   = (unsigned int*)(ws + 103432192);   // 1 KB (64 groups x 4)
  unsigned int* mctr   = (unsigned int*)(ws + 103433216);   // 512 B (32 groups x 4)
  float* out = (float*)d_out;

  hipLaunchKernelGGL(prep_a, dim3(2097), dim3(256), 0, stream,
                     We, Wei, Wm, Wmi, bm, bmi, bmh, be, bei, beh,
                     Wse, Wre, WcmGI, bcmGI, bceGI, Afin, ectr, mctr);
  hipLaunchKernelGGL(prep_b, dim3(512), dim3(256), 0, stream,
                     Wmh, Weh, Wse, Wre, pWmh, pWeh, pWsr);
  {
    void* margs[] = {(void*)&X, (void*)&WcmGI, (void*)&bcmGI, (void*)&pWmh,
                     (void*)&hm, (void*)&mb, (void*)&mctr};
    hipLaunchCooperativeKernel(reinterpret_cast<void*>(motion_lstm),
                               dim3(128), dim3(512), margs, 0, stream);
  }
  hipLaunchKernelGGL(gsr_gemm, dim3(315*16), dim3(256), 0, stream,
                     hm, pWsr, gsr);
  {
    void* eargs[] = {(void*)&gsr, (void*)&bceGI, (void*)&pWeh, (void*)&Wf,
                     (void*)&hb, (void*)&Afin, (void*)&ectr};
    hipLaunchCooperativeKernel(reinterpret_cast<void*>(edge_lstm),
                               dim3(256), dim3(512), eargs, 0, stream);
  }
  hipLaunchKernelGGL(finalize, dim3(25), dim3(256), 0, stream,
                     Afin, bfp, out);
}

// Round 5
// 1650.007 us; speedup vs baseline: 1.3183x; 1.3183x over previous
//
#include <hip/hip_runtime.h>
#include <stdint.h>

// Problem constants
#define NBATCH 16
#define NNODE  20
#define TSTEPS 63      // T-1
#define NEDGE  380
#define HID    256
#define RS     280     // hst row stride in shorts (16B-aligned rows, phase-clean b128)

typedef __bf16 bf16x8 __attribute__((ext_vector_type(8)));
typedef float  f32x4  __attribute__((ext_vector_type(4)));

__device__ __forceinline__ float bf2f(unsigned short u){
  union { unsigned int i; float f; } v; v.i = ((unsigned int)u) << 16; return v.f;
}
__device__ __forceinline__ unsigned short f2bf(float f){
  union { float f; unsigned int i; } v; v.f = f;
  return (unsigned short)((v.i + 0x7FFFu + ((v.i >> 16) & 1u)) >> 16);
}
__device__ __forceinline__ bf16x8 as_frag(uint4 v){
  union { uint4 u; bf16x8 b; } c; c.u = v; return c.b;
}
__device__ __forceinline__ float sigmf(float x){ return 1.0f/(1.0f+__expf(-x)); }
__device__ __forceinline__ float tanh_f(float x){ float e=__expf(2.0f*x); return (e-1.0f)/(e+1.0f); }

// Relaxed agent-scope ops: per-access sc1 (LLC = coherence point), no cache-wide inv/wb.
__device__ __forceinline__ unsigned long long load_ax(const unsigned long long* p){
  return __hip_atomic_load(p, __ATOMIC_RELAXED, __HIP_MEMORY_SCOPE_AGENT);
}
__device__ __forceinline__ void store_ax(unsigned long long* p, unsigned long long v){
  __hip_atomic_store(p, v, __ATOMIC_RELAXED, __HIP_MEMORY_SCOPE_AGENT);
}
__device__ __forceinline__ void wait_vm0(){ asm volatile("s_waitcnt vmcnt(0)" ::: "memory"); }

// In-register 4x4 gate transpose among lanes cl^1, cl^2 (gate-interleaved cols).
// in: v[r] = preact(row quad*4+r) for (gate=cl&3, hsub=cl>>2)
// out: v[g] = preact gate g for (row quad*4+(cl&3), hsub=cl>>2)   [proven R4]
__device__ __forceinline__ void xpose4(f32x4& v, int cl){
  float s0 = __shfl_xor((float)v[1], 1), s1 = __shfl_xor((float)v[0], 1);
  float s2 = __shfl_xor((float)v[3], 1), s3 = __shfl_xor((float)v[2], 1);
  bool b0 = (cl & 1);
  float a0 = b0 ? s0 : v[0], a1 = b0 ? v[1] : s1;
  float a2 = b0 ? s2 : v[2], a3 = b0 ? v[3] : s3;
  float t0 = __shfl_xor(a2, 2), t1 = __shfl_xor(a3, 2);
  float t2 = __shfl_xor(a0, 2), t3 = __shfl_xor(a1, 2);
  bool b1 = (cl & 2);
  v[0] = b1 ? t0 : a0; v[1] = b1 ? t1 : a1;
  v[2] = b1 ? a2 : t2; v[3] = b1 ? a3 : t3;
}

// ---------------------------------------------------------------------------
// prep_a: combined weights (fp32) + interleaved biases + zero counters/Afin.
__global__ __launch_bounds__(256) void prep_a(
    const float* __restrict__ We, const float* __restrict__ Wei,
    const float* __restrict__ Wm, const float* __restrict__ Wmi,
    const float* __restrict__ bm, const float* __restrict__ bmi, const float* __restrict__ bmh,
    const float* __restrict__ be, const float* __restrict__ bei, const float* __restrict__ beh,
    float* __restrict__ Wse, float* __restrict__ Wre, float* __restrict__ WcmGI,
    float* __restrict__ bcmGI, float* __restrict__ bceGI,
    float* __restrict__ Afin, unsigned int* __restrict__ ectr, unsigned int* __restrict__ mctr){
  int bid = blockIdx.x, tid = threadIdx.x;
  if (bid < 2048){
    int idx = bid*256 + tid;
    int half = idx >> 18;
    int j = idx & 262143;
    int k = j >> 10, nn = j & 1023;
    const float* Wrow = We + (half*256 + k)*128;
    float s = 0.f;
    for (int d = 0; d < 128; ++d) s += Wrow[d] * Wei[d*1024 + nn];
    (half ? Wre : Wse)[k*1024 + nn] = s;
  } else if (bid < 2064){
    int idx = (bid-2048)*256 + tid;
    int d = idx >> 10, ci = idx & 1023;
    int col = (ci & 3)*256 + (ci >> 2);
    float s = 0.f;
    for (int j = 0; j < 128; ++j) s += Wm[d*128 + j] * Wmi[j*1024 + col];
    WcmGI[idx] = s;
  } else if (bid < 2068){
    int ci = (bid-2064)*256 + tid;
    int col = (ci & 3)*256 + (ci >> 2);
    float s = bmi[col] + bmh[col];
    for (int j = 0; j < 128; ++j) s += bm[j] * Wmi[j*1024 + col];
    bcmGI[ci] = s;
  } else if (bid < 2072){
    int ci = (bid-2068)*256 + tid;
    int col = (ci & 3)*256 + (ci >> 2);
    float s = bei[col] + beh[col];
    for (int j = 0; j < 128; ++j) s += be[j] * Wei[j*1024 + col];
    bceGI[ci] = s;
  } else if (bid == 2072){
    ectr[tid] = 0u;
    if (tid < 128) mctr[tid] = 0u;
  } else {
    int idx = (bid-2073)*256 + tid;
    if (idx < NBATCH*NEDGE) Afin[idx] = 0.f;
  }
}

// ---------------------------------------------------------------------------
// prep_b packing (verified R2-R4).
__device__ __forceinline__ void pack_gi(const float* __restrict__ W,
                                        unsigned short* __restrict__ dst, int id){
  int lane = id & 63, kt = (id >> 6) & 7, tt = (id >> 9) & 1, w = (id >> 10) & 7, nb = id >> 13;
  int cl = lane & 15, q = lane >> 4;
  int gcol = (cl & 3)*256 + nb*64 + (w*2 + tt)*4 + (cl >> 2);
  int k0 = kt*32 + q*8;
  unsigned int wb[4];
  #pragma unroll
  for (int p = 0; p < 4; ++p){
    unsigned short a = f2bf(W[(k0+2*p  )*1024 + gcol]);
    unsigned short b = f2bf(W[(k0+2*p+1)*1024 + gcol]);
    wb[p] = (unsigned int)a | ((unsigned int)b << 16);
  }
  ((uint4*)dst)[id] = make_uint4(wb[0], wb[1], wb[2], wb[3]);
}

__device__ __forceinline__ void pack_one(const float* __restrict__ S,
                                         unsigned short* __restrict__ dst, int id, int n){
  int lane = id & 63, kt = (id >> 6) & 7;
  int k0 = kt*32 + ((lane >> 4) << 3);
  unsigned int wb[4];
  #pragma unroll
  for (int p = 0; p < 4; ++p){
    unsigned short a = f2bf(S[(k0+2*p  )*1024 + n]);
    unsigned short b = f2bf(S[(k0+2*p+1)*1024 + n]);
    wb[p] = (unsigned int)a | ((unsigned int)b << 16);
  }
  ((uint4*)dst)[id] = make_uint4(wb[0], wb[1], wb[2], wb[3]);
}

__global__ __launch_bounds__(256) void prep_b(
    const float* __restrict__ Wmh, const float* __restrict__ Weh,
    const float* __restrict__ Wse, const float* __restrict__ Wre,
    unsigned short* __restrict__ pWmh, unsigned short* __restrict__ pWeh,
    unsigned short* __restrict__ pWsr){
  int gid = blockIdx.x*256 + threadIdx.x;
  if (gid < 32768){
    pack_gi(Wmh, pWmh, gid);
  } else if (gid < 65536){
    pack_gi(Weh, pWeh, gid - 32768);
  } else {
    int id = gid - 65536;
    int ng = (id >> 9)*16 + (id & 15);
    const float* S = (ng < 1024) ? Wse : Wre;
    pack_one(S, pWsr, id, ng & 1023);
  }
}

// ---------------------------------------------------------------------------
// motion_lstm: grid 128 = 32 m (10 seqs) x 4 n. 512 thr = 8 waves.
// R3 sync skeleton (tid0 poll, coalesced publish, 5 barriers) + xpose4 update.
__global__ __launch_bounds__(512, 2) void motion_lstm(
    const float* __restrict__ X, const float* __restrict__ WcmGI,
    const float* __restrict__ bcmGI, const unsigned short* __restrict__ pWmh,
    unsigned short* __restrict__ hm, unsigned short* __restrict__ mb,
    unsigned int* __restrict__ mctr){
  __shared__ __align__(16) unsigned short hst[16*RS];
  __shared__ float dxs[10*252];
  __shared__ __align__(16) float sWc[4*256];
  __shared__ __align__(16) float sbc[256];
  int tid = threadIdx.x, lane = tid & 63, w = tid >> 6;
  int l15 = lane & 15, quad = lane >> 4;
  int m = blockIdx.x & 31, n = blockIdx.x >> 5;
  int s0 = m*10;
  unsigned int* ctr = mctr + m;

  uint4 wreg[2][8];
  #pragma unroll
  for (int tt = 0; tt < 2; ++tt)
    #pragma unroll
    for (int kt = 0; kt < 8; ++kt)
      wreg[tt][kt] = ((const uint4*)pWmh)[(((n*8 + w)*2 + tt)*8 + kt)*64 + lane];

  uint4 z4 = make_uint4(0,0,0,0);
  for (int i = tid; i < 560; i += 512) ((uint4*)hst)[i] = z4;
  for (int i = tid; i < 1024; i += 512) sWc[i] = WcmGI[(i >> 8)*1024 + n*256 + (i & 255)];
  if (tid < 256) sbc[tid] = bcmGI[n*256 + tid];
  for (int i = tid; i < 2520; i += 512){
    int sl = i / 252; int r = i % 252; int t = r >> 2; int d = r & 3;
    const float* Xp = X + (((size_t)(s0 + sl)*64 + t)*4 + d);
    dxs[i] = Xp[4] - Xp[0];
  }
  __syncthreads();

  float bb[2] = { sbc[(w*2+0)*16 + l15], sbc[(w*2+1)*16 + l15] };
  int row = quad*4 + (l15 & 3);
  int hsub = l15 >> 2;
  int slr = row < 10 ? row : 9;
  float ce[2] = {0.f, 0.f};

  for (int t = 0; t < TSTEPS; ++t){
    if (t > 0){
      if (tid == 0){
        unsigned int tgt = 4u*(unsigned)t;
        while (__hip_atomic_load(ctr, __ATOMIC_RELAXED, __HIP_MEMORY_SCOPE_AGENT) < tgt)
          __builtin_amdgcn_s_sleep(1);
      }
      __syncthreads();                                    // B1
      const unsigned long long* mbp = (const unsigned long long*)mb
          + ((size_t)((t-1)&1)*32 + m)*16*64;
      unsigned long long pv[2]; int po[2] = {-1,-1};
      #pragma unroll
      for (int j = 0; j < 2; ++j){
        int i = tid + j*512;                   // 0..767: 3 partner slices x 256 ull
        if (i < 768){
          int which = i >> 8, jj = i & 255;
          int r = jj >> 4, c = jj & 15;
          int np = which + (which >= n ? 1 : 0);
          pv[j] = load_ax(&mbp[(size_t)r*64 + np*16 + c]);
          po[j] = r*RS + np*64 + c*4;
        }
      }
      #pragma unroll
      for (int j = 0; j < 2; ++j)
        if (po[j] >= 0) *(unsigned long long*)&hst[po[j]] = pv[j];
    }
    __syncthreads();                                      // B2

    f32x4 acc[2];
    acc[0] = (f32x4){bb[0],bb[0],bb[0],bb[0]};
    acc[1] = (f32x4){bb[1],bb[1],bb[1],bb[1]};
    #pragma unroll
    for (int kt = 0; kt < 8; ++kt){
      bf16x8 a = as_frag(*(const uint4*)&hst[l15*RS + kt*32 + quad*8]);
      acc[0] = __builtin_amdgcn_mfma_f32_16x16x32_bf16(a, as_frag(wreg[0][kt]), acc[0], 0, 0, 0);
      acc[1] = __builtin_amdgcn_mfma_f32_16x16x32_bf16(a, as_frag(wreg[1][kt]), acc[1], 0, 0, 0);
    }
    __syncthreads();                                      // B3 (hst reads done)

    f32x4 dxv = *(const f32x4*)&dxs[slr*252 + t*4];
    #pragma unroll
    for (int tt = 0; tt < 2; ++tt){
      int tl = w*2 + tt;
      f32x4 v = acc[tt];
      xpose4(v, l15);
      #pragma unroll
      for (int d = 0; d < 4; ++d){
        f32x4 wv = *(const f32x4*)&sWc[d*256 + tl*16 + hsub*4];
        v[0] += dxv[d]*wv[0]; v[1] += dxv[d]*wv[1];
        v[2] += dxv[d]*wv[2]; v[3] += dxv[d]*wv[3];
      }
      float iv = sigmf(v[0]), fv = sigmf(v[1]), gg = tanh_f(v[2]), ov = sigmf(v[3]);
      float cc = fv*ce[tt] + iv*gg; ce[tt] = cc;
      hst[row*RS + n*64 + tl*4 + hsub] = f2bf(ov*tanh_f(cc));
    }
    __syncthreads();                                      // B4 (h writes visible)

    unsigned long long* mbc = (unsigned long long*)mb
        + ((size_t)(t&1)*32 + m)*16*64;
    if (tid < 256){
      int r = tid >> 4, c = tid & 15;
      unsigned long long v = *(const unsigned long long*)&hst[r*RS + n*64 + c*4];
      if (t < 62) store_ax(&mbc[(size_t)r*64 + n*16 + c], v);
      if (r < 10)
        *(unsigned long long*)&hm[(((size_t)(s0 + r)*63) + t)*256 + n*64 + c*4] = v;
    }
    wait_vm0();
    __syncthreads();                                      // B5 (stores drained)
    if (t < 62 && tid == 0)
      __hip_atomic_fetch_add(ctr, 1u, __ATOMIC_RELAXED, __HIP_MEMORY_SCOPE_AGENT);
  }
}

// ---------------------------------------------------------------------------
// gsr_gemm: projections of hm through combined [Wse|Wre], written directly in
// the edge xg B-frag-friendly layout gsrT[b][t][gcol(1024, gate-interleaved)][48]:
//   slots 0..19  = receiver proj (Wre), node
//   slots 24+6g+j = sender proj (Wse), node = 5g+j (j<5)
__global__ __launch_bounds__(256) void gsr_gemm(
    const unsigned short* __restrict__ hm, const unsigned short* __restrict__ pWsr,
    unsigned short* __restrict__ gsrT){
  int tid = threadIdx.x, lane = tid & 63, wid = tid >> 6;
  int l15 = lane & 15, quad = lane >> 4;
  int bm = blockIdx.x % 315, bn = blockIdx.x / 315;
  int rowbase = bm*64 + (wid >> 1)*32;
  int ntbase  = bn*8  + (wid & 1)*4;
  f32x4 acc[2][4] = {};
  #pragma unroll
  for (int kt = 0; kt < 8; ++kt){
    bf16x8 af[2];
    #pragma unroll
    for (int mt = 0; mt < 2; ++mt){
      int r = rowbase + mt*16 + l15;
      af[mt] = as_frag(*(const uint4*)&hm[(size_t)r*256 + kt*32 + quad*8]);
    }
    #pragma unroll
    for (int nt = 0; nt < 4; ++nt){
      bf16x8 bfr = as_frag(*(const uint4*)&pWsr[(((size_t)(ntbase+nt)*8 + kt)*64 + lane)*8]);
      #pragma unroll
      for (int mt = 0; mt < 2; ++mt)
        acc[mt][nt] = __builtin_amdgcn_mfma_f32_16x16x32_bf16(af[mt], bfr, acc[mt][nt], 0, 0, 0);
    }
  }
  #pragma unroll
  for (int mt = 0; mt < 2; ++mt)
    #pragma unroll
    for (int nt = 0; nt < 4; ++nt){
      int col = (ntbase+nt)*16 + l15;
      int half = col >> 10, ch = col & 1023;
      int colp = (ch & 255)*4 + (ch >> 8);
      #pragma unroll
      for (int r = 0; r < 4; ++r){
        int row = rowbase + mt*16 + quad*4 + r;
        int seq = row / 63; int t = row - seq*63;
        int b = seq / 20;  int node = seq - b*20;
        int slot = half ? node : (24 + (node/5)*6 + (node - (node/5)*5));
        gsrT[((size_t)(b*63 + t)*1024 + colp)*48 + slot] = f2bf(acc[mt][nt][r]);
      }
    }
}

// ---------------------------------------------------------------------------
// edge_lstm: grid 256 = 16 b x 4 m (95 edges) x 4 n. 512 thr = 8 waves.
// R3 sync skeleton + one-hot xg MFMA (gsrT staged with aligned copies) + xpose4.
__device__ __forceinline__ void stage_gxb(const unsigned short* __restrict__ gsrT,
                                          unsigned short* __restrict__ gx,
                                          int tid, int b, int m, int n, int tq){
  const unsigned short* base = gsrT + ((size_t)(b*63 + tq)*1024 + n*256)*48;
  #pragma unroll
  for (int j = 0; j < 2; ++j){
    int i = tid + j*512;              // 0..1023 = 256 cols x 4 chunks
    int c = i >> 2, chv = i & 3;
    const unsigned short* src = base + c*48;
    unsigned short* dst = gx + (c>>4)*640 + (c&15)*40;
    if (chv < 3){
      *(uint4*)(dst + chv*8) = *(const uint4*)(src + chv*8);
    } else {
      const unsigned int* s3 = (const unsigned int*)(src + 24 + 6*m);
      unsigned int* d3 = (unsigned int*)(dst + 24);
      d3[0] = s3[0]; d3[1] = s3[1]; d3[2] = s3[2];
    }
  }
}

__global__ __launch_bounds__(512, 2) void edge_lstm(
    const unsigned short* __restrict__ gsrT, const float* __restrict__ bceGI,
    const unsigned short* __restrict__ pWeh, const float* __restrict__ Wf,
    unsigned short* __restrict__ hb, float* __restrict__ Afin,
    unsigned int* __restrict__ ectr){
  __shared__ __align__(16) unsigned short hst[96*RS];      // 53760 B
  __shared__ __align__(16) unsigned short gxb[2][10240];   // 40960 B (16 tl x 16 cl x 40 k)
  __shared__ __align__(16) float sbce[256];
  __shared__ __align__(16) float sWf[64];
  int tid = threadIdx.x, lane = tid & 63, w = tid >> 6;
  int l15 = lane & 15, quad = lane >> 4;
  int bid = blockIdx.x;
  int n = bid >> 6, G = bid & 63, b = G >> 2, m = G & 3;
  int e0 = m*95;
  unsigned int* ctr = ectr + G;

  uint4 wreg[2][8];
  #pragma unroll
  for (int tt = 0; tt < 2; ++tt)
    #pragma unroll
    for (int kt = 0; kt < 8; ++kt)
      wreg[tt][kt] = ((const uint4*)pWeh)[(((n*8 + w)*2 + tt)*8 + kt)*64 + lane];

  // one-hot A frags for xg K-tile: k<20 -> receiver node k; k in [24,29) -> sender slot k-24
  uint4 aoh[6];
  #pragma unroll
  for (int mt = 0; mt < 6; ++mt){
    int row = mt*16 + l15;
    int e = e0 + (row < 95 ? row : 94);
    int s = e / 19; int rr = e - s*19;
    int sr = s - m*5;
    int rc = rr + (rr >= s ? 1 : 0);
    unsigned int wd[4];
    #pragma unroll
    for (int p = 0; p < 4; ++p){
      int k0 = quad*8 + 2*p, k1 = k0 + 1;
      unsigned short a0 = ((k0 < 20) ? (rc == k0) : (k0 >= 24 && k0 < 29 && sr == k0-24)) ? 0x3F80 : 0;
      unsigned short a1 = ((k1 < 20) ? (rc == k1) : (k1 >= 24 && k1 < 29 && sr == k1-24)) ? 0x3F80 : 0;
      wd[p] = (unsigned int)a0 | ((unsigned int)a1 << 16);
    }
    aoh[mt] = make_uint4(wd[0], wd[1], wd[2], wd[3]);
  }

  if (tid < 256) sbce[tid] = bceGI[n*256 + tid];
  if (tid < 64)  sWf[tid]  = Wf[n*64 + tid];
  uint4 z4 = make_uint4(0,0,0,0);
  for (int i = tid; i < 3360; i += 512) ((uint4*)hst)[i] = z4;
  for (int i = tid; i < 2560; i += 512) ((uint4*)gxb)[i] = z4;
  __syncthreads();
  stage_gxb(gsrT, &gxb[0][0], tid, b, m, n, 0);
  __syncthreads();

  float bb[2]  = { sbce[(w*2+0)*16 + l15], sbce[(w*2+1)*16 + l15] };
  float wfr[2] = { sWf[(w*2+0)*4 + (l15>>2)], sWf[(w*2+1)*4 + (l15>>2)] };

  float ce[2][6]; float epi[6];
  #pragma unroll
  for (int mt = 0; mt < 6; ++mt){ ce[0][mt] = 0.f; ce[1][mt] = 0.f; epi[mt] = 0.f; }

  for (int t = 0; t < TSTEPS; ++t){
    int par = t & 1, nxt = par ^ 1;
    if (t > 0){
      if (tid == 0){
        unsigned int tgt = 4u*(unsigned)t;
        while (__hip_atomic_load(ctr, __ATOMIC_RELAXED, __HIP_MEMORY_SCOPE_AGENT) < tgt)
          __builtin_amdgcn_s_sleep(1);
      }
      __syncthreads();                                    // B1
      const unsigned long long* hbp = (const unsigned long long*)hb
          + (((size_t)((t-1)&1)*16 + b)*4 + m)*96*64;
      unsigned long long pv[9]; int po[9];
      #pragma unroll
      for (int j = 0; j < 9; ++j){
        int i = tid + j*512;                   // 0..4607: 3 partner slices x 1536 ull
        int which = i / 1536, jj = i - which*1536;
        int r = jj >> 4, c = jj & 15;
        int np = which + (which >= n ? 1 : 0);
        pv[j] = load_ax(&hbp[(size_t)r*64 + np*16 + c]);
        po[j] = r*RS + np*64 + c*4;
      }
      #pragma unroll
      for (int j = 0; j < 9; ++j)
        *(unsigned long long*)&hst[po[j]] = pv[j];
    }
    if (t + 1 < TSTEPS)
      stage_gxb(gsrT, &gxb[nxt][0], tid, b, m, n, t+1);
    __syncthreads();                                      // B2

    f32x4 acc[2][6];
    #pragma unroll
    for (int mt = 0; mt < 6; ++mt){
      acc[0][mt] = (f32x4){bb[0],bb[0],bb[0],bb[0]};
      acc[1][mt] = (f32x4){bb[1],bb[1],bb[1],bb[1]};
    }
    #pragma unroll
    for (int kt = 0; kt < 8; ++kt){
      bf16x8 a[6];
      #pragma unroll
      for (int mt = 0; mt < 6; ++mt)
        a[mt] = as_frag(*(const uint4*)&hst[(mt*16 + l15)*RS + kt*32 + quad*8]);
      #pragma unroll
      for (int mt = 0; mt < 6; ++mt){
        acc[0][mt] = __builtin_amdgcn_mfma_f32_16x16x32_bf16(a[mt], as_frag(wreg[0][kt]), acc[0][mt], 0, 0, 0);
        acc[1][mt] = __builtin_amdgcn_mfma_f32_16x16x32_bf16(a[mt], as_frag(wreg[1][kt]), acc[1][mt], 0, 0, 0);
      }
    }
    {
      bf16x8 bx0 = as_frag(*(const uint4*)&gxb[par][(w*2+0)*640 + l15*40 + quad*8]);
      bf16x8 bx1 = as_frag(*(const uint4*)&gxb[par][(w*2+1)*640 + l15*40 + quad*8]);
      #pragma unroll
      for (int mt = 0; mt < 6; ++mt){
        acc[0][mt] = __builtin_amdgcn_mfma_f32_16x16x32_bf16(as_frag(aoh[mt]), bx0, acc[0][mt], 0, 0, 0);
        acc[1][mt] = __builtin_amdgcn_mfma_f32_16x16x32_bf16(as_frag(aoh[mt]), bx1, acc[1][mt], 0, 0, 0);
      }
    }
    __syncthreads();                                      // B3 (hst reads done)

    #pragma unroll
    for (int tt = 0; tt < 2; ++tt){
      int tl = w*2 + tt;
      #pragma unroll
      for (int mt = 0; mt < 6; ++mt){
        f32x4 v = acc[tt][mt];
        xpose4(v, l15);
        float iv = sigmf(v[0]), fv = sigmf(v[1]), gg = tanh_f(v[2]), ov = sigmf(v[3]);
        float cc = fv*ce[tt][mt] + iv*gg; ce[tt][mt] = cc;
        float h = ov*tanh_f(cc);
        if (t < 62){
          int row = mt*16 + quad*4 + (l15 & 3);
          hst[row*RS + n*64 + tl*4 + (l15>>2)] = f2bf(h);
        } else {
          epi[mt] += h * wfr[tt];
        }
      }
    }
    if (t < 62){
      __syncthreads();                                    // B4 (h writes visible)
      unsigned long long* hbc = (unsigned long long*)hb
          + (((size_t)(t&1)*16 + b)*4 + m)*96*64;
      #pragma unroll
      for (int j = 0; j < 3; ++j){
        int i = tid + j*512;                   // 0..1535 ull, coalesced
        int r = i >> 4, c = i & 15;
        unsigned long long v = *(const unsigned long long*)&hst[r*RS + n*64 + c*4];
        store_ax(&hbc[(size_t)r*64 + n*16 + c], v);
      }
      wait_vm0();
      __syncthreads();                                    // B5
      if (tid == 0)
        __hip_atomic_fetch_add(ctr, 1u, __ATOMIC_RELAXED, __HIP_MEMORY_SCOPE_AGENT);
    }
  }
  // epilogue: reduce over hsub lanes (xor 4, 8), one atomic per (row, wave)
  #pragma unroll
  for (int mt = 0; mt < 6; ++mt){
    float v = epi[mt];
    v += __shfl_xor(v, 4);
    v += __shfl_xor(v, 8);
    if (l15 < 4){
      int row = mt*16 + quad*4 + l15;
      if (row < 95)
        atomicAdd(&Afin[b*380 + e0 + row], v);
    }
  }
}

// ---------------------------------------------------------------------------
// finalize
__global__ __launch_bounds__(256) void finalize(const float* __restrict__ Afin,
                                                const float* __restrict__ bfp,
                                                float* __restrict__ out){
  int idx = blockIdx.x*256 + threadIdx.x;
  if (idx >= 16*400) return;
  int b = idx / 400; int ij = idx % 400; int i = ij / 20; int j = ij % 20;
  float v = 0.f;
  if (i != j){
    int e1 = i*19 + j - (j > i ? 1 : 0);
    int e2 = j*19 + i - (i > j ? 1 : 0);
    float bf = bfp[0];
    v = 0.5f*(sigmf(Afin[b*380 + e1] + bf) + sigmf(Afin[b*380 + e2] + bf));
  }
  out[idx] = v;
}

// ---------------------------------------------------------------------------
extern "C" void kernel_launch(void* const* d_in, const int* in_sizes, int n_in,
                              void* d_out, int out_size, void* d_ws, size_t ws_size,
                              hipStream_t stream){
  (void)in_sizes; (void)n_in; (void)out_size; (void)ws_size;
  const float* X   = (const float*)d_in[0];
  const float* Wm  = (const float*)d_in[3];
  const float* bm  = (const float*)d_in[4];
  const float* Wmi = (const float*)d_in[5];
  const float* bmi = (const float*)d_in[6];
  const float* Wmh = (const float*)d_in[7];
  const float* bmh = (const float*)d_in[8];
  const float* We  = (const float*)d_in[9];
  const float* be  = (const float*)d_in[10];
  const float* Wei = (const float*)d_in[11];
  const float* bei = (const float*)d_in[12];
  const float* Weh = (const float*)d_in[13];
  const float* beh = (const float*)d_in[14];
  const float* Wf  = (const float*)d_in[15];
  const float* bfp = (const float*)d_in[16];

  char* ws = (char*)d_ws;
  float* Wse   = (float*)(ws + 0);                          // 1 MB
  float* Wre   = (float*)(ws + 1048576);                    // 1 MB
  float* WcmGI = (float*)(ws + 2097152);                    // 16 KB
  float* bcmGI = (float*)(ws + 2113536);                    // 4 KB
  float* bceGI = (float*)(ws + 2117632);                    // 4 KB
  unsigned short* pWmh = (unsigned short*)(ws + 2121728);   // 512 KB
  unsigned short* pWeh = (unsigned short*)(ws + 2646016);   // 512 KB
  unsigned short* pWsr = (unsigned short*)(ws + 3170304);   // 1 MB
  unsigned short* hm   = (unsigned short*)(ws + 4218880);   // 10.3 MB
  unsigned short* gsrT = (unsigned short*)(ws + 14540800);  // 99.1 MB (16*63*1024*48*2)
  unsigned short* hb   = (unsigned short*)(ws + 113631232); // 6.3 MB (edge exchange)
  unsigned short* mb   = hb;                                // aliased: disjoint lifetime
  float* Afin          = (float*)(ws + 119922688);          // 24 KB
  unsigned int* ectr   = (unsigned int*)(ws + 119947264);   // 1 KB
  unsigned int* mctr   = (unsigned int*)(ws + 119948288);   // 512 B
  float* out = (float*)d_out;

  hipLaunchKernelGGL(prep_a, dim3(2097), dim3(256), 0, stream,
                     We, Wei, Wm, Wmi, bm, bmi, bmh, be, bei, beh,
                     Wse, Wre, WcmGI, bcmGI, bceGI, Afin, ectr, mctr);
  hipLaunchKernelGGL(prep_b, dim3(512), dim3(256), 0, stream,
                     Wmh, Weh, Wse, Wre, pWmh, pWeh, pWsr);
  {
    void* margs[] = {(void*)&X, (void*)&WcmGI, (void*)&bcmGI, (void*)&pWmh,
                     (void*)&hm, (void*)&mb, (void*)&mctr};
    hipLaunchCooperativeKernel(reinterpret_cast<void*>(motion_lstm),
                               dim3(128), dim3(512), margs, 0, stream);
  }
  hipLaunchKernelGGL(gsr_gemm, dim3(315*16), dim3(256), 0, stream,
                     hm, pWsr, gsrT);
  {
    void* eargs[] = {(void*)&gsrT, (void*)&bceGI, (void*)&pWeh, (void*)&Wf,
                     (void*)&hb, (void*)&Afin, (void*)&ectr};
    hipLaunchCooperativeKernel(reinterpret_cast<void*>(edge_lstm),
                               dim3(256), dim3(512), eargs, 0, stream);
  }
  hipLaunchKernelGGL(finalize, dim3(25), dim3(256), 0, stream,
                     Afin, bfp, out);
}

// Round 6
// 1055.481 us; speedup vs baseline: 2.0609x; 1.5633x over previous
//
#include <hip/hip_runtime.h>
#include <stdint.h>

// Problem constants
#define NBATCH 16
#define NNODE  20
#define TSTEPS 63      // T-1
#define NEDGE  380
#define HID    256
#define RS     280     // hst row stride in shorts (16B-aligned rows, phase-clean b128)

typedef __bf16 bf16x8 __attribute__((ext_vector_type(8)));
typedef float  f32x4  __attribute__((ext_vector_type(4)));

__device__ __forceinline__ float bf2f(unsigned short u){
  union { unsigned int i; float f; } v; v.i = ((unsigned int)u) << 16; return v.f;
}
__device__ __forceinline__ unsigned short f2bf(float f){
  union { float f; unsigned int i; } v; v.f = f;
  return (unsigned short)((v.i + 0x7FFFu + ((v.i >> 16) & 1u)) >> 16);
}
__device__ __forceinline__ bf16x8 as_frag(uint4 v){
  union { uint4 u; bf16x8 b; } c; c.u = v; return c.b;
}
__device__ __forceinline__ float sigmf(float x){ return 1.0f/(1.0f+__expf(-x)); }
__device__ __forceinline__ float tanh_f(float x){ float e=__expf(2.0f*x); return (e-1.0f)/(e+1.0f); }

// Relaxed agent-scope ops: per-access sc1 (LLC = coherence point), no cache-wide inv/wb.
__device__ __forceinline__ unsigned long long load_ax(const unsigned long long* p){
  return __hip_atomic_load(p, __ATOMIC_RELAXED, __HIP_MEMORY_SCOPE_AGENT);
}
__device__ __forceinline__ void store_ax(unsigned long long* p, unsigned long long v){
  __hip_atomic_store(p, v, __ATOMIC_RELAXED, __HIP_MEMORY_SCOPE_AGENT);
}
__device__ __forceinline__ void wait_vm0(){ asm volatile("s_waitcnt vmcnt(0)" ::: "memory"); }

// In-register 4x4 gate transpose among lanes cl^1, cl^2 (gate-interleaved cols). [proven R4/R5]
__device__ __forceinline__ void xpose4(f32x4& v, int cl){
  float s0 = __shfl_xor((float)v[1], 1), s1 = __shfl_xor((float)v[0], 1);
  float s2 = __shfl_xor((float)v[3], 1), s3 = __shfl_xor((float)v[2], 1);
  bool b0 = (cl & 1);
  float a0 = b0 ? s0 : v[0], a1 = b0 ? v[1] : s1;
  float a2 = b0 ? s2 : v[2], a3 = b0 ? v[3] : s3;
  float t0 = __shfl_xor(a2, 2), t1 = __shfl_xor(a3, 2);
  float t2 = __shfl_xor(a0, 2), t3 = __shfl_xor(a1, 2);
  bool b1 = (cl & 2);
  v[0] = b1 ? t0 : a0; v[1] = b1 ? t1 : a1;
  v[2] = b1 ? a2 : t2; v[3] = b1 ? a3 : t3;
}

// ---------------------------------------------------------------------------
// prep_a: combined weights (fp32) + interleaved biases + zero counters/Afin.
__global__ __launch_bounds__(256) void prep_a(
    const float* __restrict__ We, const float* __restrict__ Wei,
    const float* __restrict__ Wm, const float* __restrict__ Wmi,
    const float* __restrict__ bm, const float* __restrict__ bmi, const float* __restrict__ bmh,
    const float* __restrict__ be, const float* __restrict__ bei, const float* __restrict__ beh,
    float* __restrict__ Wse, float* __restrict__ Wre, float* __restrict__ WcmGI,
    float* __restrict__ bcmGI, float* __restrict__ bceGI,
    float* __restrict__ Afin, unsigned int* __restrict__ ectr, unsigned int* __restrict__ mctr){
  int bid = blockIdx.x, tid = threadIdx.x;
  if (bid < 2048){
    int idx = bid*256 + tid;
    int half = idx >> 18;
    int j = idx & 262143;
    int k = j >> 10, nn = j & 1023;
    const float* Wrow = We + (half*256 + k)*128;
    float s = 0.f;
    for (int d = 0; d < 128; ++d) s += Wrow[d] * Wei[d*1024 + nn];
    (half ? Wre : Wse)[k*1024 + nn] = s;
  } else if (bid < 2064){
    int idx = (bid-2048)*256 + tid;
    int d = idx >> 10, ci = idx & 1023;
    int col = (ci & 3)*256 + (ci >> 2);
    float s = 0.f;
    for (int j = 0; j < 128; ++j) s += Wm[d*128 + j] * Wmi[j*1024 + col];
    WcmGI[idx] = s;
  } else if (bid < 2068){
    int ci = (bid-2064)*256 + tid;
    int col = (ci & 3)*256 + (ci >> 2);
    float s = bmi[col] + bmh[col];
    for (int j = 0; j < 128; ++j) s += bm[j] * Wmi[j*1024 + col];
    bcmGI[ci] = s;
  } else if (bid < 2072){
    int ci = (bid-2068)*256 + tid;
    int col = (ci & 3)*256 + (ci >> 2);
    float s = bei[col] + beh[col];
    for (int j = 0; j < 128; ++j) s += be[j] * Wei[j*1024 + col];
    bceGI[ci] = s;
  } else if (bid == 2072){
    for (int i = tid; i < 2048; i += 256) ectr[i] = 0u;   // padded: group G at G*32
    for (int i = tid; i < 1024; i += 256) mctr[i] = 0u;   // padded: group m at m*32
  } else {
    int idx = (bid-2073)*256 + tid;
    if (idx < NBATCH*NEDGE) Afin[idx] = 0.f;
  }
}

// ---------------------------------------------------------------------------
// prep_b packing (verified R2-R5).
__device__ __forceinline__ void pack_gi(const float* __restrict__ W,
                                        unsigned short* __restrict__ dst, int id){
  int lane = id & 63, kt = (id >> 6) & 7, tt = (id >> 9) & 1, w = (id >> 10) & 7, nb = id >> 13;
  int cl = lane & 15, q = lane >> 4;
  int gcol = (cl & 3)*256 + nb*64 + (w*2 + tt)*4 + (cl >> 2);
  int k0 = kt*32 + q*8;
  unsigned int wb[4];
  #pragma unroll
  for (int p = 0; p < 4; ++p){
    unsigned short a = f2bf(W[(k0+2*p  )*1024 + gcol]);
    unsigned short b = f2bf(W[(k0+2*p+1)*1024 + gcol]);
    wb[p] = (unsigned int)a | ((unsigned int)b << 16);
  }
  ((uint4*)dst)[id] = make_uint4(wb[0], wb[1], wb[2], wb[3]);
}

__device__ __forceinline__ void pack_one(const float* __restrict__ S,
                                         unsigned short* __restrict__ dst, int id, int n){
  int lane = id & 63, kt = (id >> 6) & 7;
  int k0 = kt*32 + ((lane >> 4) << 3);
  unsigned int wb[4];
  #pragma unroll
  for (int p = 0; p < 4; ++p){
    unsigned short a = f2bf(S[(k0+2*p  )*1024 + n]);
    unsigned short b = f2bf(S[(k0+2*p+1)*1024 + n]);
    wb[p] = (unsigned int)a | ((unsigned int)b << 16);
  }
  ((uint4*)dst)[id] = make_uint4(wb[0], wb[1], wb[2], wb[3]);
}

__global__ __launch_bounds__(256) void prep_b(
    const float* __restrict__ Wmh, const float* __restrict__ Weh,
    const float* __restrict__ Wse, const float* __restrict__ Wre,
    unsigned short* __restrict__ pWmh, unsigned short* __restrict__ pWeh,
    unsigned short* __restrict__ pWsr){
  int gid = blockIdx.x*256 + threadIdx.x;
  if (gid < 32768){
    pack_gi(Wmh, pWmh, gid);
  } else if (gid < 65536){
    pack_gi(Weh, pWeh, gid - 32768);
  } else {
    int id = gid - 65536;
    int ng = (id >> 9)*16 + (id & 15);
    const float* S = (ng < 1024) ? Wse : Wre;
    pack_one(S, pWsr, id, ng & 1023);
  }
}

// ---------------------------------------------------------------------------
// motion_lstm: grid 128 = 32 m (10 seqs) x 4 n. 512 thr = 8 waves.
// R3/R5 sync skeleton. hm now written T-MAJOR: hm2[(b*63+t)*20+node][256].
__global__ __launch_bounds__(512, 2) void motion_lstm(
    const float* __restrict__ X, const float* __restrict__ WcmGI,
    const float* __restrict__ bcmGI, const unsigned short* __restrict__ pWmh,
    unsigned short* __restrict__ hm, unsigned short* __restrict__ mb,
    unsigned int* __restrict__ mctr){
  __shared__ __align__(16) unsigned short hst[16*RS];
  __shared__ float dxs[10*252];
  __shared__ __align__(16) float sWc[4*256];
  __shared__ __align__(16) float sbc[256];
  int tid = threadIdx.x, lane = tid & 63, w = tid >> 6;
  int l15 = lane & 15, quad = lane >> 4;
  int m = blockIdx.x & 31, n = blockIdx.x >> 5;
  int s0 = m*10;
  unsigned int* ctr = mctr + m*32;   // padded counter

  uint4 wreg[2][8];
  #pragma unroll
  for (int tt = 0; tt < 2; ++tt)
    #pragma unroll
    for (int kt = 0; kt < 8; ++kt)
      wreg[tt][kt] = ((const uint4*)pWmh)[(((n*8 + w)*2 + tt)*8 + kt)*64 + lane];

  uint4 z4 = make_uint4(0,0,0,0);
  for (int i = tid; i < 560; i += 512) ((uint4*)hst)[i] = z4;
  for (int i = tid; i < 1024; i += 512) sWc[i] = WcmGI[(i >> 8)*1024 + n*256 + (i & 255)];
  if (tid < 256) sbc[tid] = bcmGI[n*256 + tid];
  for (int i = tid; i < 2520; i += 512){
    int sl = i / 252; int r = i % 252; int t = r >> 2; int d = r & 3;
    const float* Xp = X + (((size_t)(s0 + sl)*64 + t)*4 + d);
    dxs[i] = Xp[4] - Xp[0];
  }
  __syncthreads();

  float bb[2] = { sbc[(w*2+0)*16 + l15], sbc[(w*2+1)*16 + l15] };
  int row = quad*4 + (l15 & 3);
  int hsub = l15 >> 2;
  int slr = row < 10 ? row : 9;
  float ce[2] = {0.f, 0.f};

  for (int t = 0; t < TSTEPS; ++t){
    if (t > 0){
      if (tid == 0){
        unsigned int tgt = 4u*(unsigned)t;
        while (__hip_atomic_load(ctr, __ATOMIC_RELAXED, __HIP_MEMORY_SCOPE_AGENT) < tgt)
          __builtin_amdgcn_s_sleep(1);
      }
      __syncthreads();                                    // B1
      const unsigned long long* mbp = (const unsigned long long*)mb
          + ((size_t)((t-1)&1)*32 + m)*16*64;
      unsigned long long pv[2]; int po[2] = {-1,-1};
      #pragma unroll
      for (int j = 0; j < 2; ++j){
        int i = tid + j*512;                   // 0..767: 3 partner slices x 256 ull
        if (i < 768){
          int which = i >> 8, jj = i & 255;
          int r = jj >> 4, c = jj & 15;
          int np = which + (which >= n ? 1 : 0);
          pv[j] = load_ax(&mbp[(size_t)r*64 + np*16 + c]);
          po[j] = r*RS + np*64 + c*4;
        }
      }
      #pragma unroll
      for (int j = 0; j < 2; ++j)
        if (po[j] >= 0) *(unsigned long long*)&hst[po[j]] = pv[j];
    }
    __syncthreads();                                      // B2

    f32x4 acc[2];
    acc[0] = (f32x4){bb[0],bb[0],bb[0],bb[0]};
    acc[1] = (f32x4){bb[1],bb[1],bb[1],bb[1]};
    #pragma unroll
    for (int kt = 0; kt < 8; ++kt){
      bf16x8 a = as_frag(*(const uint4*)&hst[l15*RS + kt*32 + quad*8]);
      acc[0] = __builtin_amdgcn_mfma_f32_16x16x32_bf16(a, as_frag(wreg[0][kt]), acc[0], 0, 0, 0);
      acc[1] = __builtin_amdgcn_mfma_f32_16x16x32_bf16(a, as_frag(wreg[1][kt]), acc[1], 0, 0, 0);
    }
    __syncthreads();                                      // B3 (hst reads done)

    f32x4 dxv = *(const f32x4*)&dxs[slr*252 + t*4];
    #pragma unroll
    for (int tt = 0; tt < 2; ++tt){
      int tl = w*2 + tt;
      f32x4 v = acc[tt];
      xpose4(v, l15);
      #pragma unroll
      for (int d = 0; d < 4; ++d){
        f32x4 wv = *(const f32x4*)&sWc[d*256 + tl*16 + hsub*4];
        v[0] += dxv[d]*wv[0]; v[1] += dxv[d]*wv[1];
        v[2] += dxv[d]*wv[2]; v[3] += dxv[d]*wv[3];
      }
      float iv = sigmf(v[0]), fv = sigmf(v[1]), gg = tanh_f(v[2]), ov = sigmf(v[3]);
      float cc = fv*ce[tt] + iv*gg; ce[tt] = cc;
      hst[row*RS + n*64 + tl*4 + hsub] = f2bf(ov*tanh_f(cc));
    }
    __syncthreads();                                      // B4 (h writes visible)

    unsigned long long* mbc = (unsigned long long*)mb
        + ((size_t)(t&1)*32 + m)*16*64;
    if (tid < 256){
      int r = tid >> 4, c = tid & 15;
      unsigned long long v = *(const unsigned long long*)&hst[r*RS + n*64 + c*4];
      if (t < 62) store_ax(&mbc[(size_t)r*64 + n*16 + c], v);
      if (r < 10){
        int seq = s0 + r;
        int b2 = seq / 20, nd = seq - (seq/20)*20;
        *(unsigned long long*)&hm[(((size_t)(b2*63 + t)*20) + nd)*256 + n*64 + c*4] = v;
      }
    }
    wait_vm0();
    __syncthreads();                                      // B5 (stores drained)
    if (t < 62 && tid == 0)
      __hip_atomic_fetch_add(ctr, 1u, __ATOMIC_RELAXED, __HIP_MEMORY_SCOPE_AGENT);
  }
}

// ---------------------------------------------------------------------------
// gsr_gemm: hm2 (t-major) @ [Wse|Wre] -> gsrT records, COALESCED writes.
// Record (48 shorts, 96 B) per (bt = b*63+t, ch = gate*256+hcol):
//   shorts 0..19  = receiver proj (Wre) for nodes 0..19
//   shorts 24+6g+j = sender proj (Wse) node 5g+j (j<5), pad j=5
// M-tile 80 rows = 4 bt-groups x 20 nodes; N-tile 128; grid 252 x 16.
__global__ __launch_bounds__(256) void gsr_gemm(
    const unsigned short* __restrict__ hm, const unsigned short* __restrict__ pWsr,
    unsigned short* __restrict__ gsrT){
  __shared__ __align__(16) unsigned short scol[128*100];   // [col][row], stride 100
  int tid = threadIdx.x, lane = tid & 63, wid = tid >> 6;
  int l15 = lane & 15, quad = lane >> 4;
  int bm = blockIdx.x % 252, bn = blockIdx.x / 252;
  int rowbase = bm*80;
  f32x4 acc[5][2] = {};
  #pragma unroll
  for (int kt = 0; kt < 8; ++kt){
    bf16x8 af[5];
    #pragma unroll
    for (int mt = 0; mt < 5; ++mt)
      af[mt] = as_frag(*(const uint4*)&hm[(size_t)(rowbase + mt*16 + l15)*256 + kt*32 + quad*8]);
    #pragma unroll
    for (int j = 0; j < 2; ++j){
      int ntg = bn*8 + wid*2 + j;
      bf16x8 bfr = as_frag(*(const uint4*)&pWsr[(((size_t)ntg*8 + kt)*64 + lane)*8]);
      #pragma unroll
      for (int mt = 0; mt < 5; ++mt)
        acc[mt][j] = __builtin_amdgcn_mfma_f32_16x16x32_bf16(af[mt], bfr, acc[mt][j], 0, 0, 0);
    }
  }
  // stage transposed: scol[col][row] (C-frag rows quad*4..+3 contiguous)
  #pragma unroll
  for (int mt = 0; mt < 5; ++mt)
    #pragma unroll
    for (int j = 0; j < 2; ++j){
      int colL = (wid*2 + j)*16 + l15;
      unsigned int p0 = (unsigned)f2bf(acc[mt][j][0]) | ((unsigned)f2bf(acc[mt][j][1]) << 16);
      unsigned int p1 = (unsigned)f2bf(acc[mt][j][2]) | ((unsigned)f2bf(acc[mt][j][3]) << 16);
      *(uint2*)&scol[colL*100 + mt*16 + quad*4] = make_uint2(p0, p1);
    }
  __syncthreads();
  int half = bn >> 3;   // 0 = Wse (sender), 1 = Wre (receiver)
  #pragma unroll
  for (int rep = 0; rep < 2; ++rep){
    int i = tid + rep*256;
    int btl = i >> 7, colL = i & 127;
    const unsigned short* sp = &scol[colL*100 + btl*20];
    uint2 u0 = *(const uint2*)(sp);
    uint2 u1 = *(const uint2*)(sp+4);
    uint2 u2 = *(const uint2*)(sp+8);
    uint2 u3 = *(const uint2*)(sp+12);
    uint2 u4 = *(const uint2*)(sp+16);
    unsigned short* dp = gsrT + ((size_t)(bm*4 + btl)*1024 + (bn&7)*128 + colL)*48;
    if (half){
      *(uint4*)(dp)      = make_uint4(u0.x, u0.y, u1.x, u1.y);
      *(uint4*)(dp + 8)  = make_uint4(u2.x, u2.y, u3.x, u3.y);
      *(uint2*)(dp + 16) = u4;
    } else {
      unsigned int o0 = u0.x, o1 = u0.y, o2 = u1.x & 0xffffu;
      unsigned int o3 = (u1.x >> 16) | (u1.y << 16);
      unsigned int o4 = (u1.y >> 16) | (u2.x << 16);
      unsigned int o5 = u2.x >> 16;
      unsigned int o6 = u2.y, o7 = u3.x, o8 = u3.y & 0xffffu;
      unsigned int o9 = (u3.y >> 16) | (u4.x << 16);
      unsigned int o10 = (u4.x >> 16) | (u4.y << 16);
      unsigned int o11 = u4.y >> 16;
      *(uint4*)(dp + 24) = make_uint4(o0, o1, o2, o3);
      *(uint4*)(dp + 32) = make_uint4(o4, o5, o6, o7);
      *(uint4*)(dp + 40) = make_uint4(o8, o9, o10, o11);
    }
  }
}

// ---------------------------------------------------------------------------
// edge_lstm: grid 256 = 16 b x 4 m (95 edges) x 4 n. 512 thr = 8 waves.
// R5 structure; stage reads contiguous records, GI mapping folded into LDS dst.
__device__ __forceinline__ void stage_gxb(const unsigned short* __restrict__ gsrT,
                                          unsigned short* __restrict__ gx,
                                          int tid, int b, int m, int n, int tq){
  const unsigned short* base = gsrT + (size_t)(b*63 + tq)*1024*48;
  int c = tid >> 1, chv = tid & 1;
  int g = c >> 6, hh = c & 63;
  const unsigned short* src = base + (size_t)((g << 8) + (n << 6) + hh)*48;
  unsigned short* dst = gx + (hh >> 2)*640 + (((hh & 3) << 2) + g)*40;
  if (chv == 0){
    *(uint4*)(dst)      = *(const uint4*)(src);
    *(uint4*)(dst + 8)  = *(const uint4*)(src + 8);
    *(uint2*)(dst + 16) = *(const uint2*)(src + 16);
  } else {
    const unsigned int* s3 = (const unsigned int*)(src + 24 + 6*m);
    unsigned int* d3 = (unsigned int*)(dst + 24);
    d3[0] = s3[0]; d3[1] = s3[1]; d3[2] = s3[2];
  }
}

__global__ __launch_bounds__(512, 2) void edge_lstm(
    const unsigned short* __restrict__ gsrT, const float* __restrict__ bceGI,
    const unsigned short* __restrict__ pWeh, const float* __restrict__ Wf,
    unsigned short* __restrict__ hb, float* __restrict__ Afin,
    unsigned int* __restrict__ ectr){
  __shared__ __align__(16) unsigned short hst[96*RS];      // 53760 B
  __shared__ __align__(16) unsigned short gxb[2][10240];   // 40960 B (16 tl x 16 cl x 40 k)
  __shared__ __align__(16) float sbce[256];
  __shared__ __align__(16) float sWf[64];
  int tid = threadIdx.x, lane = tid & 63, w = tid >> 6;
  int l15 = lane & 15, quad = lane >> 4;
  int bid = blockIdx.x;
  int n = bid >> 6, G = bid & 63, b = G >> 2, m = G & 3;
  int e0 = m*95;
  unsigned int* ctr = ectr + G*32;   // padded counter (one per 128 B)

  uint4 wreg[2][8];
  #pragma unroll
  for (int tt = 0; tt < 2; ++tt)
    #pragma unroll
    for (int kt = 0; kt < 8; ++kt)
      wreg[tt][kt] = ((const uint4*)pWeh)[(((n*8 + w)*2 + tt)*8 + kt)*64 + lane];

  // one-hot A frags for xg K-tile: k<20 -> receiver node k; k = 24+sr -> sender
  uint4 aoh[6];
  #pragma unroll
  for (int mt = 0; mt < 6; ++mt){
    int row = mt*16 + l15;
    int e = e0 + (row < 95 ? row : 94);
    int s = e / 19; int rr = e - s*19;
    int sr = s - m*5;
    int rc = rr + (rr >= s ? 1 : 0);
    unsigned int wd[4];
    #pragma unroll
    for (int p = 0; p < 4; ++p){
      int k0 = quad*8 + 2*p, k1 = k0 + 1;
      unsigned short a0 = ((k0 < 20) ? (rc == k0) : (k0 >= 24 && k0 < 29 && sr == k0-24)) ? 0x3F80 : 0;
      unsigned short a1 = ((k1 < 20) ? (rc == k1) : (k1 >= 24 && k1 < 29 && sr == k1-24)) ? 0x3F80 : 0;
      wd[p] = (unsigned int)a0 | ((unsigned int)a1 << 16);
    }
    aoh[mt] = make_uint4(wd[0], wd[1], wd[2], wd[3]);
  }

  if (tid < 256) sbce[tid] = bceGI[n*256 + tid];
  if (tid < 64)  sWf[tid]  = Wf[n*64 + tid];
  uint4 z4 = make_uint4(0,0,0,0);
  for (int i = tid; i < 3360; i += 512) ((uint4*)hst)[i] = z4;
  for (int i = tid; i < 2560; i += 512) ((uint4*)gxb)[i] = z4;
  __syncthreads();
  stage_gxb(gsrT, &gxb[0][0], tid, b, m, n, 0);
  __syncthreads();

  float bb[2]  = { sbce[(w*2+0)*16 + l15], sbce[(w*2+1)*16 + l15] };
  float wfr[2] = { sWf[(w*2+0)*4 + (l15>>2)], sWf[(w*2+1)*4 + (l15>>2)] };

  float ce[2][6]; float epi[6];
  #pragma unroll
  for (int mt = 0; mt < 6; ++mt){ ce[0][mt] = 0.f; ce[1][mt] = 0.f; epi[mt] = 0.f; }

  for (int t = 0; t < TSTEPS; ++t){
    int par = t & 1, nxt = par ^ 1;
    if (t > 0){
      if (tid == 0){
        unsigned int tgt = 4u*(unsigned)t;
        while (__hip_atomic_load(ctr, __ATOMIC_RELAXED, __HIP_MEMORY_SCOPE_AGENT) < tgt)
          __builtin_amdgcn_s_sleep(1);
      }
      __syncthreads();                                    // B1
      const unsigned long long* hbp = (const unsigned long long*)hb
          + (((size_t)((t-1)&1)*16 + b)*4 + m)*96*64;
      unsigned long long pv[9]; int po[9];
      #pragma unroll
      for (int j = 0; j < 9; ++j){
        int i = tid + j*512;                   // 0..4607: 3 partner slices x 1536 ull
        int which = i / 1536, jj = i - which*1536;
        int r = jj >> 4, c = jj & 15;
        int np = which + (which >= n ? 1 : 0);
        pv[j] = load_ax(&hbp[(size_t)r*64 + np*16 + c]);
        po[j] = r*RS + np*64 + c*4;
      }
      #pragma unroll
      for (int j = 0; j < 9; ++j)
        *(unsigned long long*)&hst[po[j]] = pv[j];
    }
    if (t + 1 < TSTEPS)
      stage_gxb(gsrT, &gxb[nxt][0], tid, b, m, n, t+1);
    __syncthreads();                                      // B2

    f32x4 acc[2][6];
    #pragma unroll
    for (int mt = 0; mt < 6; ++mt){
      acc[0][mt] = (f32x4){bb[0],bb[0],bb[0],bb[0]};
      acc[1][mt] = (f32x4){bb[1],bb[1],bb[1],bb[1]};
    }
    #pragma unroll
    for (int kt = 0; kt < 8; ++kt){
      bf16x8 a[6];
      #pragma unroll
      for (int mt = 0; mt < 6; ++mt)
        a[mt] = as_frag(*(const uint4*)&hst[(mt*16 + l15)*RS + kt*32 + quad*8]);
      #pragma unroll
      for (int mt = 0; mt < 6; ++mt){
        acc[0][mt] = __builtin_amdgcn_mfma_f32_16x16x32_bf16(a[mt], as_frag(wreg[0][kt]), acc[0][mt], 0, 0, 0);
        acc[1][mt] = __builtin_amdgcn_mfma_f32_16x16x32_bf16(a[mt], as_frag(wreg[1][kt]), acc[1][mt], 0, 0, 0);
      }
    }
    {
      bf16x8 bx0 = as_frag(*(const uint4*)&gxb[par][(w*2+0)*640 + l15*40 + quad*8]);
      bf16x8 bx1 = as_frag(*(const uint4*)&gxb[par][(w*2+1)*640 + l15*40 + quad*8]);
      #pragma unroll
      for (int mt = 0; mt < 6; ++mt){
        acc[0][mt] = __builtin_amdgcn_mfma_f32_16x16x32_bf16(as_frag(aoh[mt]), bx0, acc[0][mt], 0, 0, 0);
        acc[1][mt] = __builtin_amdgcn_mfma_f32_16x16x32_bf16(as_frag(aoh[mt]), bx1, acc[1][mt], 0, 0, 0);
      }
    }
    __syncthreads();                                      // B3 (hst reads done)

    #pragma unroll
    for (int tt = 0; tt < 2; ++tt){
      int tl = w*2 + tt;
      #pragma unroll
      for (int mt = 0; mt < 6; ++mt){
        f32x4 v = acc[tt][mt];
        xpose4(v, l15);
        float iv = sigmf(v[0]), fv = sigmf(v[1]), gg = tanh_f(v[2]), ov = sigmf(v[3]);
        float cc = fv*ce[tt][mt] + iv*gg; ce[tt][mt] = cc;
        float h = ov*tanh_f(cc);
        if (t < 62){
          int row = mt*16 + quad*4 + (l15 & 3);
          hst[row*RS + n*64 + tl*4 + (l15>>2)] = f2bf(h);
        } else {
          epi[mt] += h * wfr[tt];
        }
      }
    }
    if (t < 62){
      __syncthreads();                                    // B4 (h writes visible)
      unsigned long long* hbc = (unsigned long long*)hb
          + (((size_t)(t&1)*16 + b)*4 + m)*96*64;
      #pragma unroll
      for (int j = 0; j < 3; ++j){
        int i = tid + j*512;                   // 0..1535 ull, coalesced
        int r = i >> 4, c = i & 15;
        unsigned long long v = *(const unsigned long long*)&hst[r*RS + n*64 + c*4];
        store_ax(&hbc[(size_t)r*64 + n*16 + c], v);
      }
      wait_vm0();
      __syncthreads();                                    // B5
      if (tid == 0)
        __hip_atomic_fetch_add(ctr, 1u, __ATOMIC_RELAXED, __HIP_MEMORY_SCOPE_AGENT);
    }
  }
  // epilogue: reduce over hsub lanes (xor 4, 8), one atomic per (row, wave)
  #pragma unroll
  for (int mt = 0; mt < 6; ++mt){
    float v = epi[mt];
    v += __shfl_xor(v, 4);
    v += __shfl_xor(v, 8);
    if (l15 < 4){
      int row = mt*16 + quad*4 + l15;
      if (row < 95)
        atomicAdd(&Afin[b*380 + e0 + row], v);
    }
  }
}

// ---------------------------------------------------------------------------
// finalize
__global__ __launch_bounds__(256) void finalize(const float* __restrict__ Afin,
                                                const float* __restrict__ bfp,
                                                float* __restrict__ out){
  int idx = blockIdx.x*256 + threadIdx.x;
  if (idx >= 16*400) return;
  int b = idx / 400; int ij = idx % 400; int i = ij / 20; int j = ij % 20;
  float v = 0.f;
  if (i != j){
    int e1 = i*19 + j - (j > i ? 1 : 0);
    int e2 = j*19 + i - (i > j ? 1 : 0);
    float bf = bfp[0];
    v = 0.5f*(sigmf(Afin[b*380 + e1] + bf) + sigmf(Afin[b*380 + e2] + bf));
  }
  out[idx] = v;
}

// ---------------------------------------------------------------------------
extern "C" void kernel_launch(void* const* d_in, const int* in_sizes, int n_in,
                              void* d_out, int out_size, void* d_ws, size_t ws_size,
                              hipStream_t stream){
  (void)in_sizes; (void)n_in; (void)out_size; (void)ws_size;
  const float* X   = (const float*)d_in[0];
  const float* Wm  = (const float*)d_in[3];
  const float* bm  = (const float*)d_in[4];
  const float* Wmi = (const float*)d_in[5];
  const float* bmi = (const float*)d_in[6];
  const float* Wmh = (const float*)d_in[7];
  const float* bmh = (const float*)d_in[8];
  const float* We  = (const float*)d_in[9];
  const float* be  = (const float*)d_in[10];
  const float* Wei = (const float*)d_in[11];
  const float* bei = (const float*)d_in[12];
  const float* Weh = (const float*)d_in[13];
  const float* beh = (const float*)d_in[14];
  const float* Wf  = (const float*)d_in[15];
  const float* bfp = (const float*)d_in[16];

  char* ws = (char*)d_ws;
  float* Wse   = (float*)(ws + 0);                          // 1 MB
  float* Wre   = (float*)(ws + 1048576);                    // 1 MB
  float* WcmGI = (float*)(ws + 2097152);                    // 16 KB
  float* bcmGI = (float*)(ws + 2113536);                    // 4 KB
  float* bceGI = (float*)(ws + 2117632);                    // 4 KB
  unsigned short* pWmh = (unsigned short*)(ws + 2121728);   // 512 KB
  unsigned short* pWeh = (unsigned short*)(ws + 2646016);   // 512 KB
  unsigned short* pWsr = (unsigned short*)(ws + 3170304);   // 1 MB
  unsigned short* hm   = (unsigned short*)(ws + 4218880);   // 10.3 MB (t-major)
  unsigned short* gsrT = (unsigned short*)(ws + 14540800);  // 99.1 MB (16*63*1024 recs x 96 B)
  unsigned short* hb   = (unsigned short*)(ws + 113631232); // 6.3 MB (edge exchange)
  unsigned short* mb   = hb;                                // aliased: disjoint lifetime
  float* Afin          = (float*)(ws + 119922688);          // 24 KB
  unsigned int* ectr   = (unsigned int*)(ws + 119947264);   // 8 KB (64 groups x 128 B)
  unsigned int* mctr   = (unsigned int*)(ws + 119955456);   // 4 KB (32 groups x 128 B)
  float* out = (float*)d_out;

  hipLaunchKernelGGL(prep_a, dim3(2097), dim3(256), 0, stream,
                     We, Wei, Wm, Wmi, bm, bmi, bmh, be, bei, beh,
                     Wse, Wre, WcmGI, bcmGI, bceGI, Afin, ectr, mctr);
  hipLaunchKernelGGL(prep_b, dim3(512), dim3(256), 0, stream,
                     Wmh, Weh, Wse, Wre, pWmh, pWeh, pWsr);
  {
    void* margs[] = {(void*)&X, (void*)&WcmGI, (void*)&bcmGI, (void*)&pWmh,
                     (void*)&hm, (void*)&mb, (void*)&mctr};
    hipLaunchCooperativeKernel(reinterpret_cast<void*>(motion_lstm),
                               dim3(128), dim3(512), margs, 0, stream);
  }
  hipLaunchKernelGGL(gsr_gemm, dim3(252*16), dim3(256), 0, stream,
                     hm, pWsr, gsrT);
  {
    void* eargs[] = {(void*)&gsrT, (void*)&bceGI, (void*)&pWeh, (void*)&Wf,
                     (void*)&hb, (void*)&Afin, (void*)&ectr};
    hipLaunchCooperativeKernel(reinterpret_cast<void*>(edge_lstm),
                               dim3(256), dim3(512), eargs, 0, stream);
  }
  hipLaunchKernelGGL(finalize, dim3(25), dim3(256), 0, stream,
                     Afin, bfp, out);
}